// Round 5
// baseline (139380.298 us; speedup 1.0000x reference)
//
#include <hip/hip_runtime.h>
#include <math.h>

#define S_LEN 131072
#define H 100
#define G 400   // 4*H

typedef float v2f __attribute__((ext_vector_type(2)));
typedef float v4f __attribute__((ext_vector_type(4)));

__device__ __forceinline__ float sigmoid_fast(float x) {
    return 1.0f / (1.0f + __expf(-x));
}
__device__ __forceinline__ float tanh_fast(float x) {
    return 2.0f / (1.0f + __expf(-2.0f * x)) - 1.0f;
}

// Round 2 (rule #20): runtime-indexed ext_vector arrays -> scratch alloca.
// Round 3: named regs, but invariant loads got REMATERIALIZED into the loop
//          (VGPR=72, 175KB/step re-streamed from L2, ~2000 cy/step).
// Round 4: asm pin blocked remat -> allocator SPILLED instead (VGPR=64,
//          231MB scratch write-back). Root cause in all three: regalloc
//          targets DEFAULT MAX occupancy (8 waves/EU -> 64-VGPR budget);
//          launch_bounds' 2nd arg only sets the MINIMUM.
// Fix: amdgpu_waves_per_eu(1,2) caps the occupancy TARGET at 2 waves/EU
//          -> 256-VGPR budget -> ~170 live VGPRs is fine; pin stays so the
//          values must be allocated, not rematted.
__global__ __launch_bounds__(448)
__attribute__((amdgpu_waves_per_eu(1, 2)))
void lstm_seq_kernel(
    const float* __restrict__ x,      // [S]
    const float* __restrict__ W_ih,   // [400]  (400x1)
    const float* __restrict__ W_hh,   // [400,100] row-major
    const float* __restrict__ b_ih,   // [400]
    const float* __restrict__ b_hh,   // [400]
    const float* __restrict__ W_out,  // [100]  (1x100)
    const float* __restrict__ b_out,  // [1]
    float* __restrict__ out)          // [1]
{
    __shared__ __align__(16) float h_lds[112];       // hidden state (100 used)
    __shared__ __align__(16) float act_lds[4][112];  // activated gates i,f,g,o

    const int t = threadIdx.x;
    const bool worker = (t < G);
    const int gidx = (t < G) ? (t / H) : 3;  // gate block 0..3
    const int rowid = worker ? t : (G - 1);  // threads 400-447 shadow row 399

    // ---- 25 NAMED v4f weight registers: W_hh row (100 floats) ----
    v4f w0, w1, w2, w3, w4, w5, w6, w7, w8, w9, w10, w11, w12,
        w13, w14, w15, w16, w17, w18, w19, w20, w21, w22, w23, w24;
    const float* wr = W_hh + rowid * H;     // 400*rowid bytes -> 16B aligned
#define LOADW(i) w##i = *(const v4f*)(wr + 4 * (i))
    LOADW(0);  LOADW(1);  LOADW(2);  LOADW(3);  LOADW(4);
    LOADW(5);  LOADW(6);  LOADW(7);  LOADW(8);  LOADW(9);
    LOADW(10); LOADW(11); LOADW(12); LOADW(13); LOADW(14);
    LOADW(15); LOADW(16); LOADW(17); LOADW(18); LOADW(19);
    LOADW(20); LOADW(21); LOADW(22); LOADW(23); LOADW(24);
#undef LOADW
    // Pin: asm-defined values cannot be rematerialized back into the loop.
    asm volatile("" : "+v"(w0), "+v"(w1), "+v"(w2), "+v"(w3), "+v"(w4),
                      "+v"(w5), "+v"(w6), "+v"(w7), "+v"(w8), "+v"(w9),
                      "+v"(w10), "+v"(w11), "+v"(w12), "+v"(w13), "+v"(w14),
                      "+v"(w15), "+v"(w16), "+v"(w17), "+v"(w18), "+v"(w19),
                      "+v"(w20), "+v"(w21), "+v"(w22), "+v"(w23), "+v"(w24));

    const float wih  = W_ih[rowid];
    const float bsum = b_ih[rowid] + b_hh[rowid];
    float* act_slot = &act_lds[gidx][rowid - gidx * H];

    float c = 0.0f;                    // cell state, owned by threads 0..99
    if (t < H) h_lds[t] = 0.0f;
    __syncthreads();

    const v4f* hv = (const v4f*)h_lds;

    float xv_next = x[0];              // software-pipelined uniform input load

    for (int step = 0; step < S_LEN; ++step) {
        float xv = xv_next;
        int nxt = (step + 1 < S_LEN) ? (step + 1) : step;
        xv_next = x[nxt];              // issue early; latency hides under matvec

        // ---- matvec: gate = W_hh[row,:] @ h  (4 named v2f chains,
        //      v2f halves to encourage v_pk_fma_f32 formation) ----
        v2f a0 = {0.f, 0.f}, a1 = {0.f, 0.f}, a2 = {0.f, 0.f}, a3 = {0.f, 0.f};
#define FMA4(i, accA, accB)                                                   \
        {   v4f h4 = hv[i];                                                   \
            v2f wlo = {w##i.x, w##i.y}, whi = {w##i.z, w##i.w};               \
            v2f hlo = {h4.x, h4.y},     hhi = {h4.z, h4.w};                   \
            accA = __builtin_elementwise_fma(wlo, hlo, accA);                 \
            accB = __builtin_elementwise_fma(whi, hhi, accB); }
        FMA4(0,  a0, a1); FMA4(1,  a2, a3); FMA4(2,  a0, a1); FMA4(3,  a2, a3);
        FMA4(4,  a0, a1); FMA4(5,  a2, a3); FMA4(6,  a0, a1); FMA4(7,  a2, a3);
        FMA4(8,  a0, a1); FMA4(9,  a2, a3); FMA4(10, a0, a1); FMA4(11, a2, a3);
        FMA4(12, a0, a1); FMA4(13, a2, a3); FMA4(14, a0, a1); FMA4(15, a2, a3);
        FMA4(16, a0, a1); FMA4(17, a2, a3); FMA4(18, a0, a1); FMA4(19, a2, a3);
        FMA4(20, a0, a1); FMA4(21, a2, a3); FMA4(22, a0, a1); FMA4(23, a2, a3);
        FMA4(24, a0, a1);
#undef FMA4
        v2f s = (a0 + a1) + (a2 + a3);
        float gate = (s.x + s.y) + __builtin_fmaf(xv, wih, bsum);
        // activate in the parallel phase (distributes the transcendentals)
        float a = (gidx == 2) ? tanh_fast(gate) : sigmoid_fast(gate);
        if (worker) *act_slot = a;
        __syncthreads();               // gates ready

        if (t < H) {
            float ig = act_lds[0][t];
            float fg = act_lds[1][t];
            float gg = act_lds[2][t];
            float og = act_lds[3][t];
            c = fg * c + ig * gg;
            h_lds[t] = og * tanh_fast(c);
        }
        __syncthreads();               // h ready for next step
    }

    if (t == 0) {
        float s = b_out[0];
        #pragma unroll 4
        for (int j = 0; j < H; ++j) s += W_out[j] * h_lds[j];
        out[0] = s;
    }
}

extern "C" void kernel_launch(void* const* d_in, const int* in_sizes, int n_in,
                              void* d_out, int out_size, void* d_ws, size_t ws_size,
                              hipStream_t stream) {
    const float* x     = (const float*)d_in[0];
    const float* W_ih  = (const float*)d_in[1];
    const float* W_hh  = (const float*)d_in[2];
    const float* b_ih  = (const float*)d_in[3];
    const float* b_hh  = (const float*)d_in[4];
    const float* W_out = (const float*)d_in[5];
    const float* b_out = (const float*)d_in[6];
    float* out = (float*)d_out;

    lstm_seq_kernel<<<1, 448, 0, stream>>>(x, W_ih, W_hh, b_ih, b_hh,
                                           W_out, b_out, out);
}

// Round 6
// 94658.929 us; speedup vs baseline: 1.4724x; 1.4724x over previous
//
#include <hip/hip_runtime.h>
#include <math.h>

#define S_LEN 131072
#define H 100
#define NROW 400            // 4*H gate rows
#define NWORK 800           // 2 threads per row
#define BLOCK 960           // 15 waves: 800 workers + 100 updaters + spare

typedef _Float16 f16;
typedef _Float16 h2 __attribute__((ext_vector_type(2)));
typedef _Float16 h8 __attribute__((ext_vector_type(8)));

// Rounds 1-5 lesson: the AMDGPU backend targets 8 waves/EU (64-VGPR budget)
// regardless of launch_bounds/waves_per_eu hints. 100 f32 weights/thread can
// NEVER be register-resident under that budget (remat at 72 VGPR -> L2-BW
// bound ~1640cy/step; pinned -> scratch spill). Fix: fit the budget.
// 2 threads/row, f16-packed weights = 25 VGPRs; v_dot2_f32_f16 gives 2 MACs
// per instr with EXACT f32 accumulation (f16 products are exact in f32).
// Only w and h are f16 (gates/c/acts stay f32): predicted |err| ~3e-4 < 1.08e-3.
__global__ __launch_bounds__(BLOCK) void lstm_seq_kernel(
    const float* __restrict__ x,      // [S]
    const float* __restrict__ W_ih,   // [400]
    const float* __restrict__ W_hh,   // [400,100] row-major
    const float* __restrict__ b_ih,   // [400]
    const float* __restrict__ b_hh,   // [400]
    const float* __restrict__ W_out,  // [100]
    const float* __restrict__ b_out,  // [1]
    float* __restrict__ out)          // [1]
{
    __shared__ __align__(16) f16 h16[2][56];  // h as f16: two 16B-aligned 50-half banks
    __shared__ float act[4][112];             // activated gates i,f,g,o
    __shared__ float h32[112];                // h as f32 (final output only)

    const int t = threadIdx.x;
    const bool worker  = (t < NWORK);
    const bool updater = (t >= NWORK) && (t < NWORK + H);

    const int row  = worker ? (t >> 1) : 0;   // clamp keeps init loads in-bounds
    const int half = t & 1;                   // which 50-col half of the row
    const int gidx = row / H;                 // gate 0=i 1=f 2=g 3=o
    const int rowm = row - gidx * H;
    const bool is_tanh_gate = (gidx == 2);

    // ---- pack this thread's 50 weight cols into 25 f16x2 registers (RNE) ----
    const float* wr = W_hh + row * H + half * 50;
    h2 w0, w1, w2, w3, w4, w5, w6, w7, w8, w9, w10, w11, w12,
       w13, w14, w15, w16, w17, w18, w19, w20, w21, w22, w23, w24;
#define LW(i) w##i = (h2){(f16)wr[2*(i)], (f16)wr[2*(i)+1]}
    LW(0);  LW(1);  LW(2);  LW(3);  LW(4);  LW(5);  LW(6);  LW(7);  LW(8);
    LW(9);  LW(10); LW(11); LW(12); LW(13); LW(14); LW(15); LW(16); LW(17);
    LW(18); LW(19); LW(20); LW(21); LW(22); LW(23); LW(24);
#undef LW
    // cheap insurance vs rematerialization (we are UNDER budget, so no spill)
    asm volatile("" : "+v"(w0), "+v"(w1), "+v"(w2), "+v"(w3), "+v"(w4),
                      "+v"(w5), "+v"(w6), "+v"(w7), "+v"(w8), "+v"(w9),
                      "+v"(w10), "+v"(w11), "+v"(w12), "+v"(w13), "+v"(w14),
                      "+v"(w15), "+v"(w16), "+v"(w17), "+v"(w18), "+v"(w19),
                      "+v"(w20), "+v"(w21), "+v"(w22), "+v"(w23), "+v"(w24));

    const float wih  = W_ih[row];             // used by even lanes only
    const float bsum = b_ih[row] + b_hh[row];

    // updater-side state
    const int u = t - NWORK;                  // valid when updater
    float c = 0.0f;
    f16* h16_slot = &h16[0][0];
    if (updater) h16_slot = (u < 50) ? &h16[0][u] : &h16[1][u - 50];

    if (t < 56) { h16[0][t] = (f16)0.0f; h16[1][t] = (f16)0.0f; }
    __syncthreads();

    float xv_next = x[0];                     // software-pipelined uniform load

    union H8 { h8 v; h2 p[4]; };              // constant-indexed -> SROA-safe

    for (int step = 0; step < S_LEN; ++step) {
        float xv = xv_next;
        int nxt = (step + 1 < S_LEN) ? (step + 1) : step;
        xv_next = x[nxt];

        if (worker) {
            const f16* hb = h16[half];
            H8 v0, v1, v2, v3, v4, v5;
            v0.v = *(const h8*)(hb);          // ds_read_b128, 2-addr broadcast
            v1.v = *(const h8*)(hb + 8);
            v2.v = *(const h8*)(hb + 16);
            v3.v = *(const h8*)(hb + 24);
            v4.v = *(const h8*)(hb + 32);
            v5.v = *(const h8*)(hb + 40);
            h2 vt = *(const h2*)(hb + 48);    // last 2 halves

            float a0 = 0.f, a1 = 0.f, a2 = 0.f, a3 = 0.f;
#define DOT8(vv, wa, wb, wc, wd)                                          \
            a0 = __builtin_amdgcn_fdot2(wa, vv.p[0], a0, false);          \
            a1 = __builtin_amdgcn_fdot2(wb, vv.p[1], a1, false);          \
            a2 = __builtin_amdgcn_fdot2(wc, vv.p[2], a2, false);          \
            a3 = __builtin_amdgcn_fdot2(wd, vv.p[3], a3, false);
            DOT8(v0, w0,  w1,  w2,  w3)
            DOT8(v1, w4,  w5,  w6,  w7)
            DOT8(v2, w8,  w9,  w10, w11)
            DOT8(v3, w12, w13, w14, w15)
            DOT8(v4, w16, w17, w18, w19)
            DOT8(v5, w20, w21, w22, w23)
#undef DOT8
            a0 = __builtin_amdgcn_fdot2(w24, vt, a0, false);

            float tot = (a0 + a1) + (a2 + a3);
            tot += __shfl_xor(tot, 1, 64);    // combine the two row-halves

            if (half == 0) {
                float gate = tot + __builtin_fmaf(xv, wih, bsum);
                // one exp for both: sigmoid(g) or tanh(g)=2*sigmoid(2g)-1
                float z = is_tanh_gate ? 2.0f * gate : gate;
                float r = 1.0f / (1.0f + __expf(-z));
                act[gidx][rowm] = is_tanh_gate ? (2.0f * r - 1.0f) : r;
            }
        }
        __syncthreads();                      // gates ready

        if (updater) {
            float ig = act[0][u];
            float fg = act[1][u];
            float gg = act[2][u];
            float og = act[3][u];
            c = __builtin_fmaf(fg, c, ig * gg);
            float r = 1.0f / (1.0f + __expf(-2.0f * c));   // tanh(c)
            float hval = og * (2.0f * r - 1.0f);
            h32[u] = hval;
            *h16_slot = (f16)hval;            // RNE convert for next matvec
        }
        __syncthreads();                      // h ready for next step
    }

    if (t == 0) {
        float s = b_out[0];
        #pragma unroll 4
        for (int j = 0; j < H; ++j) s = __builtin_fmaf(W_out[j], h32[j], s);
        out[0] = s;
    }
}

extern "C" void kernel_launch(void* const* d_in, const int* in_sizes, int n_in,
                              void* d_out, int out_size, void* d_ws, size_t ws_size,
                              hipStream_t stream) {
    const float* x     = (const float*)d_in[0];
    const float* W_ih  = (const float*)d_in[1];
    const float* W_hh  = (const float*)d_in[2];
    const float* b_ih  = (const float*)d_in[3];
    const float* b_hh  = (const float*)d_in[4];
    const float* W_out = (const float*)d_in[5];
    const float* b_out = (const float*)d_in[6];
    float* out = (float*)d_out;

    lstm_seq_kernel<<<1, BLOCK, 0, stream>>>(x, W_ih, W_hh, b_ih, b_hh,
                                             W_out, b_out, out);
}